// Round 2
// baseline (1620.440 us; speedup 1.0000x reference)
//
#include <hip/hip_runtime.h>
#include <math.h>

#define TT 250
#define BT 256
#define HN 128
#define ON 20
#define KIN 700

// ws layout (float offsets)
#define XIN_OFF 0            // 250*256*128 = 8192000 floats
#define W22_OFF 8192000      // 16384 floats (premasked w_h2h2)
#define ZROW_OFF 8208384     // 128 floats of zeros (dummy prefetch target)

// ---------------------------------------------------------------------------
// prep: w22m = w_h2h2 * mask[1]; zero the dummy row
// ---------------------------------------------------------------------------
__global__ __launch_bounds__(256) void prep_kernel(const float* __restrict__ w_h2h2,
                                                   const float* __restrict__ mask,
                                                   float* __restrict__ ws) {
    int i = blockIdx.x * 256 + threadIdx.x;
    if (i < HN * HN) ws[W22_OFF + i] = w_h2h2[i] * mask[HN * HN + i];
    int z = i - HN * HN;
    if (z >= 0 && z < HN) ws[ZROW_OFF + z] = 0.f;
}

// ---------------------------------------------------------------------------
// input projection: xin[t][b][h] = x[b][t][:] @ w_ih1[:,h] + b_ih1[h]
// ---------------------------------------------------------------------------
__global__ __launch_bounds__(256) void gemm_in(const float* __restrict__ x,
                                               const float* __restrict__ w,
                                               const float* __restrict__ bias,
                                               float* __restrict__ xin) {
    __shared__ __align__(16) float As[20 * 68];
    __shared__ __align__(16) float Ws[20 * 128];
    const int tid = threadIdx.x;
    const int m0 = blockIdx.x * 64;
    const int r0 = (tid >> 5) * 8;
    const int c0 = (tid & 31) * 4;

    float4 acc[8];
#pragma unroll
    for (int r = 0; r < 8; r++) { acc[r].x = 0.f; acc[r].y = 0.f; acc[r].z = 0.f; acc[r].w = 0.f; }

    for (int k0 = 0; k0 < KIN; k0 += 20) {
        __syncthreads();
#pragma unroll
        for (int i = 0; i < 5; i++) {
            int idx = tid + i * 256;
            int row = idx / 20, kk = idx % 20;
            As[kk * 68 + row] = x[(m0 + row) * KIN + k0 + kk];
        }
#pragma unroll
        for (int i = 0; i < 10; i++) Ws[tid + i * 256] = w[k0 * 128 + tid + i * 256];
        __syncthreads();

#pragma unroll
        for (int kk = 0; kk < 20; kk++) {
            float4 wv = *(const float4*)&Ws[kk * 128 + c0];
            float a[8];
            *(float4*)&a[0] = *(const float4*)&As[kk * 68 + r0];
            *(float4*)&a[4] = *(const float4*)&As[kk * 68 + r0 + 4];
#pragma unroll
            for (int r = 0; r < 8; r++) {
                acc[r].x += a[r] * wv.x; acc[r].y += a[r] * wv.y;
                acc[r].z += a[r] * wv.z; acc[r].w += a[r] * wv.w;
            }
        }
    }

    const float4 bv = *(const float4*)&bias[c0];
#pragma unroll
    for (int r = 0; r < 8; r++) {
        int m = m0 + r0 + r;
        int t = m % TT, bb = m / TT;
        float4 o;
        o.x = acc[r].x + bv.x; o.y = acc[r].y + bv.y;
        o.z = acc[r].z + bv.z; o.w = acc[r].w + bv.w;
        *(float4*)&xin[(t * BT + bb) * HN + c0] = o;
    }
}

// ---------------------------------------------------------------------------
// scan v2: 256 thr/block (4 waves). Waves 0-1 = "main" LIF state machine
// (w11/w12 gathers from LDS, 2 barriers/step). Waves 2-3 = "helper": compute
// w22 column-sums from global (mask known one step ahead; w22 is L1-resident)
// AND own the readout/om/softmax (mask also known at window start). Softmax
// via register shuffles (1 exp/lane, no barrier).
// ---------------------------------------------------------------------------
__device__ __forceinline__ unsigned long long rfl64(unsigned long long v) {
    unsigned lo = (unsigned)__builtin_amdgcn_readfirstlane((int)(unsigned)v);
    unsigned hi = (unsigned)__builtin_amdgcn_readfirstlane((int)(unsigned)(v >> 32));
    return ((unsigned long long)hi << 32) | lo;
}

// batched sparse column sum from LDS, 16 outstanding loads per batch
__device__ __forceinline__ float sparse16(const float* __restrict__ wl, int stride,
                                          const float* __restrict__ zl,
                                          unsigned long long m0, unsigned long long m1,
                                          int j) {
    float acc = 0.f;
    while (m0 | m1) {
        float pg[16];
#pragma unroll
        for (int i = 0; i < 16; i++) {
            const float* p;
            if (m0)      { int h = __builtin_ctzll(m0); m0 &= m0 - 1; p = wl + h * stride; }
            else if (m1) { int h = __builtin_ctzll(m1); m1 &= m1 - 1; p = wl + (h + 64) * stride; }
            else p = zl;
            pg[i] = p[j];
        }
        float s0 = (pg[0] + pg[1]) + (pg[2] + pg[3]);
        float s1 = (pg[4] + pg[5]) + (pg[6] + pg[7]);
        float s2 = (pg[8] + pg[9]) + (pg[10] + pg[11]);
        float s3 = (pg[12] + pg[13]) + (pg[14] + pg[15]);
        acc += (s0 + s1) + (s2 + s3);
    }
    return acc;
}

__global__ __launch_bounds__(256) void snn_scan(
    const float* __restrict__ xin, const float* __restrict__ w22m,
    const float* __restrict__ zrow, const float* __restrict__ mask,
    const float* __restrict__ w_h1h1, const float* __restrict__ b_h1h1,
    const float* __restrict__ w_h1h2, const float* __restrict__ b_h1h2,
    const float* __restrict__ b_h2h2, const float* __restrict__ w_h2o,
    const float* __restrict__ b_h2o, const float* __restrict__ tau_adp1,
    const float* __restrict__ tau_adp2, const float* __restrict__ taum1,
    const float* __restrict__ taum2, const float* __restrict__ taumo,
    const float* __restrict__ h1m0, const float* __restrict__ h2m0,
    const float* __restrict__ om0, float* __restrict__ out) {
    extern __shared__ float smem[];
    float* w11s  = smem;                 // 16384
    float* w12s  = smem + 16384;         // 16384
    float* whos  = smem + 32768;         // 2560
    float* g2buf = smem + 35328;         // 128
    unsigned long long* m1sh = (unsigned long long*)(smem + 35456); // 2
    unsigned long long* m2sh = (unsigned long long*)(smem + 35460); // 2
    float* redsh = smem + 35464;         // 4
    float* zlds  = smem + 35468;         // 128  -> total 35596 f = 142384 B

    const int tid = threadIdx.x;
    const int b = blockIdx.x;
    const bool is_main = tid < 128;
    const int j = tid & 127;     // main: neuron. helper: w22 column.
    const int jj = tid - 128;    // helper lane id (jj<20 owns readout)

    float pn = 0.f;  // A-norm partial (block 0 only)
    for (int i = tid; i < HN * HN; i += 256) {
        float v = w_h1h1[i] * mask[i];
        w11s[i] = v;
        w12s[i] = w_h1h2[i];
        if (b == 0) pn += fabsf(v) + fabsf(w22m[i]);
    }
    for (int i = tid; i < HN * ON; i += 256) whos[i] = w_h2o[i];
    if (tid < HN) zlds[tid] = 0.f;

    // ---- main-role state ----
    float a1 = 0.f, r1 = 0.f, a2 = 0.f, r2 = 0.f, bj11 = 0.f, bj12 = 0.f, bj22 = 0.f;
    float h1m = 0.f, h2m = 0.f, b1 = 0.01f, b2 = 0.01f, h1s = 0.f, h2s = 0.f;
    float s1c = 0.f, s2c = 0.f, xt = 0.f;
    unsigned long long m1p0 = 0, m1p1 = 0;
    if (is_main) {
        a1 = expf(-1.f / taum1[j]);
        r1 = expf(-1.f / tau_adp1[j]);
        a2 = expf(-1.f / taum2[j]);
        r2 = expf(-1.f / tau_adp2[j]);
        bj11 = b_h1h1[j];
        bj12 = b_h1h2[j];
        bj22 = b_h2h2[j];
        h1m = h1m0[b * HN + j];
        h2m = h2m0[b * HN + j];
        xt = xin[b * HN + j];   // t = 0
    }
    // ---- helper-role state ----
    float om = 0.f, accj = 0.f, ao = 0.f, bjo = 0.f;
    unsigned long long m2c0 = 0, m2c1 = 0;
    if (!is_main && jj < ON) {
        ao  = expf(-1.f / taumo[jj]);
        bjo = b_h2o[jj];
        om  = om0[b * ON + jj];
    }

    __syncthreads();

    for (int t = 0; t < TT; t++) {
        if (is_main) {
            // ---- phase A: layer 1 ----
            const int tn = (t < TT - 1) ? t + 1 : t;
            const float xnext = xin[(tn * BT + b) * HN + j];
            float i1 = xt + bj11 + sparse16(w11s, HN, zlds, m1p0, m1p1, j);
            b1 = r1 * b1 + (1.f - r1) * h1s;
            const float B1 = 0.01f + 1.8f * b1;
            h1m = a1 * h1m + (1.f - a1) * i1 - B1 * h1s;
            const float sp1 = (h1m - B1 > 0.f) ? 1.f : 0.f;
            h1s = sp1; s1c += sp1;
            unsigned long long bal1 = __ballot(sp1 > 0.f);
            if ((tid & 63) == 0) m1sh[tid >> 6] = bal1;
            xt = xnext;
        } else {
            // ---- helper: w22 gather (for step t) + readout (for step t-1) ----
            unsigned long long mm0 = m2c0, mm1 = m2c1;
            float pf[32];
#pragma unroll
            for (int i = 0; i < 32; i++) {
                const float* p;
                if (mm0)      { int h = __builtin_ctzll(mm0); mm0 &= mm0 - 1; p = w22m + (h << 7); }
                else if (mm1) { int h = __builtin_ctzll(mm1); mm1 &= mm1 - 1; p = w22m + ((h + 64) << 7); }
                else p = zrow;
                pf[i] = p[j];
            }
            // readout for step t-1 (uses the same mask m2c = h2s(t-1)); wave 2 only
            if (jj < 64 && t >= 1) {
                if (jj < ON) {
                    float io = bjo + sparse16(whos, ON, zlds, m2c0, m2c1, jj);
                    om = ao * om + (1.f - ao) * io;
                }
                if (t - 1 > 10) {
                    float val = (jj < ON) ? om : -3.4e38f;
                    float mx = val;
#pragma unroll
                    for (int m = 16; m >= 1; m >>= 1) mx = fmaxf(mx, __shfl_xor(mx, m, 32));
                    float e = (jj < ON) ? __expf(om - mx) : 0.f;
                    float se = e;
#pragma unroll
                    for (int m = 16; m >= 1; m >>= 1) se += __shfl_xor(se, m, 32);
                    if (jj < ON) accj += e / se;
                }
            }
            // consume prefetched w22 rows + overflow
            float g;
            {
                float s0 = 0.f, s1 = 0.f, s2 = 0.f, s3 = 0.f;
#pragma unroll
                for (int i = 0; i < 32; i += 4) { s0 += pf[i]; s1 += pf[i + 1]; s2 += pf[i + 2]; s3 += pf[i + 3]; }
                g = (s0 + s1) + (s2 + s3);
                while (mm0 | mm1) {
                    float pg[16];
#pragma unroll
                    for (int i = 0; i < 16; i++) {
                        const float* p;
                        if (mm0)      { int h = __builtin_ctzll(mm0); mm0 &= mm0 - 1; p = w22m + (h << 7); }
                        else if (mm1) { int h = __builtin_ctzll(mm1); mm1 &= mm1 - 1; p = w22m + ((h + 64) << 7); }
                        else p = zrow;
                        pg[i] = p[j];
                    }
                    float t0 = (pg[0] + pg[1]) + (pg[2] + pg[3]);
                    float t1 = (pg[4] + pg[5]) + (pg[6] + pg[7]);
                    float t2 = (pg[8] + pg[9]) + (pg[10] + pg[11]);
                    float t3 = (pg[12] + pg[13]) + (pg[14] + pg[15]);
                    g += (t0 + t1) + (t2 + t3);
                }
            }
            g2buf[j] = g;
        }
        __syncthreads();  // B1: m1 masks + g2buf ready

        if (is_main) {
            // ---- phase B: layer 2 ----
            const unsigned long long m1n0 = rfl64(m1sh[0]);
            const unsigned long long m1n1 = rfl64(m1sh[1]);
            float i2 = bj12 + bj22 + sparse16(w12s, HN, zlds, m1n0, m1n1, j) + g2buf[j];
            b2 = r2 * b2 + (1.f - r2) * h2s;
            const float B2 = 0.01f + 1.8f * b2;
            h2m = a2 * h2m + (1.f - a2) * i2 - B2 * h2s;
            const float sp2 = (h2m - B2 > 0.f) ? 1.f : 0.f;
            h2s = sp2; s2c += sp2;
            unsigned long long bal2 = __ballot(sp2 > 0.f);
            if ((tid & 63) == 0) m2sh[tid >> 6] = bal2;
            m1p0 = m1n0; m1p1 = m1n1;
        }
        __syncthreads();  // B2: m2 masks ready for helper

        if (!is_main) { m2c0 = rfl64(m2sh[0]); m2c1 = rfl64(m2sh[1]); }
    }

    // ---- outputs: [acc 256x20][s1 256x128][s2 256x128][A_norm] ----
    if (is_main) {
        out[5120 + b * HN + j] = s1c * (1.f / 250.f);
        out[5120 + 32768 + b * HN + j] = s2c * (1.f / 250.f);
    } else if (jj < 64) {
        // final readout, step 249
        if (jj < ON) {
            float io = bjo + sparse16(whos, ON, zlds, m2c0, m2c1, jj);
            om = ao * om + (1.f - ao) * io;
        }
        float val = (jj < ON) ? om : -3.4e38f;
        float mx = val;
#pragma unroll
        for (int m = 16; m >= 1; m >>= 1) mx = fmaxf(mx, __shfl_xor(mx, m, 32));
        float e = (jj < ON) ? __expf(om - mx) : 0.f;
        float se = e;
#pragma unroll
        for (int m = 16; m >= 1; m >>= 1) se += __shfl_xor(se, m, 32);
        if (jj < ON) out[b * ON + jj] = accj + e / se;
    }

    if (b == 0) {
#pragma unroll
        for (int off = 32; off > 0; off >>= 1) pn += __shfl_down(pn, off);
        if ((tid & 63) == 0) redsh[tid >> 6] = pn;
        __syncthreads();
        if (tid == 0) out[70656] = redsh[0] + redsh[1] + redsh[2] + redsh[3];
    }
}

// ---------------------------------------------------------------------------
extern "C" void kernel_launch(void* const* d_in, const int* in_sizes, int n_in,
                              void* d_out, int out_size, void* d_ws, size_t ws_size,
                              hipStream_t stream) {
    const float* x        = (const float*)d_in[0];
    const float* mask     = (const float*)d_in[1];
    const float* w_ih1    = (const float*)d_in[2];
    const float* b_ih1    = (const float*)d_in[3];
    const float* w_h1h1   = (const float*)d_in[4];
    const float* b_h1h1   = (const float*)d_in[5];
    const float* w_h1h2   = (const float*)d_in[6];
    const float* b_h1h2   = (const float*)d_in[7];
    const float* w_h2h2   = (const float*)d_in[8];
    const float* b_h2h2   = (const float*)d_in[9];
    const float* w_h2o    = (const float*)d_in[10];
    const float* b_h2o    = (const float*)d_in[11];
    const float* tau_adp1 = (const float*)d_in[12];
    const float* tau_adp2 = (const float*)d_in[13];
    const float* taum1    = (const float*)d_in[14];
    const float* taum2    = (const float*)d_in[15];
    const float* taumo    = (const float*)d_in[16];
    const float* h1m0     = (const float*)d_in[17];
    const float* h2m0     = (const float*)d_in[18];
    const float* om0      = (const float*)d_in[19];
    float* out = (float*)d_out;
    float* ws  = (float*)d_ws;

    float* xin  = ws + XIN_OFF;
    float* w22m = ws + W22_OFF;
    float* zrow = ws + ZROW_OFF;

    prep_kernel<<<65, 256, 0, stream>>>(w_h2h2, mask, ws);
    gemm_in<<<1000, 256, 0, stream>>>(x, w_ih1, b_ih1, xin);

    hipFuncSetAttribute(reinterpret_cast<const void*>(snn_scan),
                        hipFuncAttributeMaxDynamicSharedMemorySize, 142384);
    snn_scan<<<256, 256, 142384, stream>>>(xin, w22m, zrow, mask, w_h1h1, b_h1h1,
                                           w_h1h2, b_h1h2, b_h2h2, w_h2o, b_h2o,
                                           tau_adp1, tau_adp2, taum1, taum2, taumo,
                                           h1m0, h2m0, om0, out);
}

// Round 3
// 1056.509 us; speedup vs baseline: 1.5338x; 1.5338x over previous
//
#include <hip/hip_runtime.h>
#include <math.h>

#define TT 250
#define BT 256
#define HN 128
#define ON 20
#define KIN 700

// ws: xin = 250*256*128 floats at offset 0
#define XIN_OFF 0

typedef __attribute__((ext_vector_type(8))) short bf16x8;
typedef __attribute__((ext_vector_type(4))) float f32x4;

__device__ __forceinline__ unsigned short bf16rne(float f) {
    unsigned u = __float_as_uint(f);
    unsigned r = u + 0x7fffu + ((u >> 16) & 1u);
    return (unsigned short)(r >> 16);
}

// ---------------------------------------------------------------------------
// input projection: xin[t][b][h] = x[b][t][:] @ w_ih1[:,h] + b_ih1[h] + b_h1h1[h]
// (b_h1h1 folded in so the scan's layer-1 update needs no extra constant)
// ---------------------------------------------------------------------------
__global__ __launch_bounds__(256) void gemm_in(const float* __restrict__ x,
                                               const float* __restrict__ w,
                                               const float* __restrict__ bias1,
                                               const float* __restrict__ bias2,
                                               float* __restrict__ xin) {
    __shared__ __align__(16) float As[20 * 68];
    __shared__ __align__(16) float Ws[20 * 128];
    const int tid = threadIdx.x;
    const int m0 = blockIdx.x * 64;
    const int r0 = (tid >> 5) * 8;
    const int c0 = (tid & 31) * 4;

    float4 acc[8];
#pragma unroll
    for (int r = 0; r < 8; r++) { acc[r].x = 0.f; acc[r].y = 0.f; acc[r].z = 0.f; acc[r].w = 0.f; }

    for (int k0 = 0; k0 < KIN; k0 += 20) {
        __syncthreads();
#pragma unroll
        for (int i = 0; i < 5; i++) {
            int idx = tid + i * 256;
            int row = idx / 20, kk = idx % 20;
            As[kk * 68 + row] = x[(m0 + row) * KIN + k0 + kk];
        }
#pragma unroll
        for (int i = 0; i < 10; i++) Ws[tid + i * 256] = w[k0 * 128 + tid + i * 256];
        __syncthreads();

#pragma unroll
        for (int kk = 0; kk < 20; kk++) {
            float4 wv = *(const float4*)&Ws[kk * 128 + c0];
            float a[8];
            *(float4*)&a[0] = *(const float4*)&As[kk * 68 + r0];
            *(float4*)&a[4] = *(const float4*)&As[kk * 68 + r0 + 4];
#pragma unroll
            for (int r = 0; r < 8; r++) {
                acc[r].x += a[r] * wv.x; acc[r].y += a[r] * wv.y;
                acc[r].z += a[r] * wv.z; acc[r].w += a[r] * wv.w;
            }
        }
    }

    const float4 b1 = *(const float4*)&bias1[c0];
    const float4 b2 = *(const float4*)&bias2[c0];
#pragma unroll
    for (int r = 0; r < 8; r++) {
        int m = m0 + r0 + r;
        int t = m % TT, bb = m / TT;
        float4 o;
        o.x = acc[r].x + b1.x + b2.x; o.y = acc[r].y + b1.y + b2.y;
        o.z = acc[r].z + b1.z + b2.z; o.w = acc[r].w + b1.w + b2.w;
        *(float4*)&xin[(t * BT + bb) * HN + c0] = o;
    }
}

// ---------------------------------------------------------------------------
// scan v3: 16 blocks x 256 thr, 16 batch rows per block. Dense MFMA recurrent
// matmuls with hi/lo-bf16 weight fragments resident in registers (spikes are
// {0,1} -> exact bf16 A operand). No data-dependent latency in the loop.
//
// Slot map (wave -> 8 register fragment slots of (matrix, ntile)):
//   mats: 0=W11(masked) 1=W22(masked) 2=W12 3=WHO(128x20, zero-padded) 4=none
//   phase A computes W11->Ibuf, W22->G2buf, WHO->Obuf  (A operand: S1p/S2p/S2p)
//   phase C computes W12->Ibuf                          (A operand: S1 new)
// ---------------------------------------------------------------------------
__device__ const int SLOT_MAT[4][8] = {
    {0,0,0,0,0,0,2,2},
    {1,1,1,1,1,1,2,2},
    {2,2,2,2,0,0,1,1},
    {3,3,4,4,4,4,4,4}};
__device__ const int SLOT_NT[4][8] = {
    {0,1,2,3,4,5,4,5},
    {0,1,2,3,4,5,6,7},
    {0,1,2,3,6,7,6,7},
    {0,1,0,0,0,0,0,0}};

#define IST 132   // I-buffer row stride (pad vs 128 to break bank alignment)

__global__ __launch_bounds__(256, 1) void snn_scan(
    const float* __restrict__ xin, const float* __restrict__ mask,
    const float* __restrict__ w_h1h1, const float* __restrict__ w_h1h2,
    const float* __restrict__ b_h1h2, const float* __restrict__ w_h2h2,
    const float* __restrict__ b_h2h2, const float* __restrict__ w_h2o,
    const float* __restrict__ b_h2o, const float* __restrict__ tau_adp1,
    const float* __restrict__ tau_adp2, const float* __restrict__ taum1,
    const float* __restrict__ taum2, const float* __restrict__ taumo,
    const float* __restrict__ h1m0, const float* __restrict__ h2m0,
    const float* __restrict__ om0, float* __restrict__ out) {
    __shared__ __align__(16) unsigned short sA1[256 * 8];  // spike A-frags, layer 1
    __shared__ __align__(16) unsigned short sA2[256 * 8];  // spike A-frags, layer 2
    __shared__ __align__(16) float Ibuf[16 * IST];         // I1 (phase A) / I12 (phase C)
    __shared__ __align__(16) float G2buf[16 * IST];        // S2_prev @ W22
    __shared__ __align__(16) float Obuf[16 * IST];         // S2_prev @ WHO
    __shared__ float red[8];

    const int tid = threadIdx.x;
    const int wv = tid >> 6;
    const int lane = tid & 63;
    const int q = lane >> 4;       // MFMA quad
    const int li = lane & 15;
    const int r0 = blockIdx.x * 16;

    // ---------------- weight fragments (register-resident, hi/lo bf16) -----
    bf16x8 whi[8][4], wlo[8][4];
    int s_mat[8], s_nt[8];
#pragma unroll
    for (int s = 0; s < 8; s++) { s_mat[s] = SLOT_MAT[wv][s]; s_nt[s] = SLOT_NT[wv][s]; }

    float pn = 0.f;  // A_norm partial
#pragma unroll
    for (int s = 0; s < 8; s++) {
        const int mat = s_mat[s];
        const float* src = (mat == 0) ? w_h1h1 : (mat == 1) ? w_h2h2
                          : (mat == 2) ? w_h1h2 : w_h2o;
        const int ncols = (mat == 3) ? ON : HN;
        const float* msk = (mat == 0) ? mask : (mat == 1) ? (mask + HN * HN) : (const float*)0;
        const int col = s_nt[s] * 16 + li;
#pragma unroll
        for (int kt = 0; kt < 4; kt++) {
#pragma unroll
            for (int j = 0; j < 8; j++) {
                const int k = kt * 32 + q * 8 + j;
                float v = 0.f;
                if (mat != 4 && col < ncols) {
                    v = src[k * ncols + col];
                    if (msk) v *= msk[k * HN + col];
                }
                if (mat == 0 || mat == 1) pn += fabsf(v);
                unsigned short h = bf16rne(v);
                float vh = __uint_as_float((unsigned)h << 16);
                unsigned short l16 = bf16rne(v - vh);
                whi[s][kt][j] = (short)h;
                wlo[s][kt][j] = (short)l16;
            }
        }
    }

    // slot roles
    bool actA[8], actC[8], useA2[8];
    float* dstA[8];
#pragma unroll
    for (int s = 0; s < 8; s++) {
        const int mat = s_mat[s];
        actA[s] = (mat == 0) | (mat == 1) | (mat == 3);
        actC[s] = (mat == 2);
        useA2[s] = (mat == 1) | (mat == 3);
        dstA[s] = (mat == 1) ? G2buf : (mat == 3) ? Obuf : Ibuf;
    }

    // ---------------- update-thread state (8 elements: row um, cols 8uc..) --
    const int um = tid & 15;
    const int uc = tid >> 4;
    const int hb = 8 * uc;

    float a1c[8], r1c[8], a2c[8], r2c[8], c2[8];
    float h1m[8], h2m[8], b1[8], b2[8], xt[8];
    unsigned s1cp[4] = {0, 0, 0, 0}, s2cp[4] = {0, 0, 0, 0};
    unsigned s1b = 0, s2b = 0;
#pragma unroll
    for (int i = 0; i < 8; i++) {
        const int h = hb + i;
        a1c[i] = expf(-1.f / taum1[h]);
        r1c[i] = expf(-1.f / tau_adp1[h]);
        a2c[i] = expf(-1.f / taum2[h]);
        r2c[i] = expf(-1.f / tau_adp2[h]);
        c2[i] = b_h1h2[h] + b_h2h2[h];
        h1m[i] = h1m0[(r0 + um) * HN + h];
        h2m[i] = h2m0[(r0 + um) * HN + h];
        b1[i] = 0.01f;
        b2[i] = 0.01f;
    }

    // wave-3 readout state: lane -> (row sm, outputs ob..ob+4)
    const int sm = lane >> 2;
    const int ob = (lane & 3) * 5;
    float om[5], accs[5], aoc[5], bjoc[5];
#pragma unroll
    for (int i = 0; i < 5; i++) {
        const int o = ob + i;
        aoc[i] = expf(-1.f / taumo[o]);
        bjoc[i] = b_h2o[o];
        om[i] = om0[(r0 + sm) * ON + o];
        accs[i] = 0.f;
    }

    // zero-init spike frags (spikes start at 0)
    bf16x8 zf;
#pragma unroll
    for (int j = 0; j < 8; j++) zf[j] = 0;
    *(bf16x8*)&sA1[tid * 8] = zf;
    *(bf16x8*)&sA2[tid * 8] = zf;

    // A_norm reduce (every block computes; block 0 stores)
#pragma unroll
    for (int off = 32; off > 0; off >>= 1) pn += __shfl_down(pn, off);
    if (lane == 0) red[wv] = pn;
    __syncthreads();
    if (tid == 0 && blockIdx.x == 0) out[70656] = red[0] + red[1] + red[2] + red[3];

    // xin for t=0
    const float* xp = xin + ((size_t)(r0 + um)) * HN + hb;
#pragma unroll
    for (int i = 0; i < 8; i++) xt[i] = xp[i];

    const bf16x8* sa1v = (const bf16x8*)sA1;
    const bf16x8* sa2v = (const bf16x8*)sA2;

    for (int t = 0; t < TT; t++) {
        // ================= phase A: W11, W22, WHO matmuls ==================
        {
            bf16x8 f1[4], f2[4];
#pragma unroll
            for (int kt = 0; kt < 4; kt++) {
                f1[kt] = sa1v[kt * 64 + lane];
                f2[kt] = sa2v[kt * 64 + lane];
            }
#pragma unroll
            for (int s = 0; s < 8; s++) {
                if (actA[s]) {
                    f32x4 acc = {0.f, 0.f, 0.f, 0.f};
#pragma unroll
                    for (int kt = 0; kt < 4; kt++) {
                        bf16x8 af = useA2[s] ? f2[kt] : f1[kt];
                        acc = __builtin_amdgcn_mfma_f32_16x16x32_bf16(af, whi[s][kt], acc, 0, 0, 0);
                        acc = __builtin_amdgcn_mfma_f32_16x16x32_bf16(af, wlo[s][kt], acc, 0, 0, 0);
                    }
                    float* d = dstA[s];
                    const int cb = s_nt[s] * 16 + li;
#pragma unroll
                    for (int r = 0; r < 4; r++) d[(q * 4 + r) * IST + cb] = acc[r];
                }
            }
        }
        __syncthreads();  // B1

        // ================= update 1 (layer-1 LIF) ==========================
        {
            float4 p0 = *(float4*)&Ibuf[um * IST + hb];
            float4 p1 = *(float4*)&Ibuf[um * IST + hb + 4];
            float I1[8] = {p0.x, p0.y, p0.z, p0.w, p1.x, p1.y, p1.z, p1.w};
            unsigned nb = 0;
            bf16x8 fr;
#pragma unroll
            for (int i = 0; i < 8; i++) {
                const float i1 = xt[i] + I1[i];  // biases folded into xin
                const bool sb = (s1b >> i) & 1;
                b1[i] = r1c[i] * b1[i] + (sb ? (1.f - r1c[i]) : 0.f);
                const float B = 0.01f + 1.8f * b1[i];
                h1m[i] = a1c[i] * h1m[i] + (1.f - a1c[i]) * i1 - (sb ? B : 0.f);
                const bool sp = (h1m[i] - B) > 0.f;
                nb |= (sp ? 1u : 0u) << i;
                s1cp[i >> 1] += sp ? (1u << (16 * (i & 1))) : 0u;
                fr[i] = sp ? (short)0x3F80 : (short)0;
            }
            s1b = nb;
            *(bf16x8*)&sA1[tid * 8] = fr;
            // prefetch xin for t+1
            const float* xn = xp + (size_t)(t < TT - 1 ? t + 1 : t) * BT * HN;
#pragma unroll
            for (int i = 0; i < 8; i++) xt[i] = xn[i];
        }
        __syncthreads();  // B2

        // ================= phase C: W12 matmul + readout/softmax ===========
        {
            if (wv != 3) {
                bf16x8 f1[4];
#pragma unroll
                for (int kt = 0; kt < 4; kt++) f1[kt] = sa1v[kt * 64 + lane];
#pragma unroll
                for (int s = 0; s < 8; s++) {
                    if (actC[s]) {
                        f32x4 acc = {0.f, 0.f, 0.f, 0.f};
#pragma unroll
                        for (int kt = 0; kt < 4; kt++) {
                            acc = __builtin_amdgcn_mfma_f32_16x16x32_bf16(f1[kt], whi[s][kt], acc, 0, 0, 0);
                            acc = __builtin_amdgcn_mfma_f32_16x16x32_bf16(f1[kt], wlo[s][kt], acc, 0, 0, 0);
                        }
                        const int cb = s_nt[s] * 16 + li;
#pragma unroll
                        for (int r = 0; r < 4; r++) Ibuf[(q * 4 + r) * IST + cb] = acc[r];
                    }
                }
            } else if (t >= 1) {
                // om update for reference step t-1 (Obuf = S2_{t-1} @ WHO)
                float e[5];
#pragma unroll
                for (int i = 0; i < 5; i++) {
                    const float io = bjoc[i] + Obuf[sm * IST + ob + i];
                    om[i] = aoc[i] * om[i] + (1.f - aoc[i]) * io;
                }
                if (t - 1 > 10) {
                    float mx = om[0];
#pragma unroll
                    for (int i = 1; i < 5; i++) mx = fmaxf(mx, om[i]);
                    mx = fmaxf(mx, __shfl_xor(mx, 1));
                    mx = fmaxf(mx, __shfl_xor(mx, 2));
                    float se = 0.f;
#pragma unroll
                    for (int i = 0; i < 5; i++) { e[i] = __expf(om[i] - mx); se += e[i]; }
                    se += __shfl_xor(se, 1);
                    se += __shfl_xor(se, 2);
#pragma unroll
                    for (int i = 0; i < 5; i++) accs[i] += e[i] / se;
                }
            }
        }
        __syncthreads();  // B3

        // ================= update 2 (layer-2 LIF) ==========================
        {
            float4 p0 = *(float4*)&Ibuf[um * IST + hb];
            float4 p1 = *(float4*)&Ibuf[um * IST + hb + 4];
            float4 g0 = *(float4*)&G2buf[um * IST + hb];
            float4 g1 = *(float4*)&G2buf[um * IST + hb + 4];
            float I12[8] = {p0.x, p0.y, p0.z, p0.w, p1.x, p1.y, p1.z, p1.w};
            float G2[8] = {g0.x, g0.y, g0.z, g0.w, g1.x, g1.y, g1.z, g1.w};
            unsigned nb = 0;
            bf16x8 fr;
#pragma unroll
            for (int i = 0; i < 8; i++) {
                const float i2 = I12[i] + G2[i] + c2[i];
                const bool sb = (s2b >> i) & 1;
                b2[i] = r2c[i] * b2[i] + (sb ? (1.f - r2c[i]) : 0.f);
                const float B = 0.01f + 1.8f * b2[i];
                h2m[i] = a2c[i] * h2m[i] + (1.f - a2c[i]) * i2 - (sb ? B : 0.f);
                const bool sp = (h2m[i] - B) > 0.f;
                nb |= (sp ? 1u : 0u) << i;
                s2cp[i >> 1] += sp ? (1u << (16 * (i & 1))) : 0u;
                fr[i] = sp ? (short)0x3F80 : (short)0;
            }
            s2b = nb;
            *(bf16x8*)&sA2[tid * 8] = fr;
        }
        __syncthreads();  // B4
    }

    // ---------------- final readout (step 249) + outputs -------------------
    if (wv == 3) {
        bf16x8 f2[4];
#pragma unroll
        for (int kt = 0; kt < 4; kt++) f2[kt] = sa2v[kt * 64 + lane];
#pragma unroll
        for (int s = 0; s < 8; s++) {
            if (s_mat[s] == 3) {
                f32x4 acc = {0.f, 0.f, 0.f, 0.f};
#pragma unroll
                for (int kt = 0; kt < 4; kt++) {
                    acc = __builtin_amdgcn_mfma_f32_16x16x32_bf16(f2[kt], whi[s][kt], acc, 0, 0, 0);
                    acc = __builtin_amdgcn_mfma_f32_16x16x32_bf16(f2[kt], wlo[s][kt], acc, 0, 0, 0);
                }
                const int cb = s_nt[s] * 16 + li;
#pragma unroll
                for (int r = 0; r < 4; r++) Obuf[(q * 4 + r) * IST + cb] = acc[r];
            }
        }
        // same-wave LDS round-trip (compiler inserts lgkmcnt wait)
        float e[5];
#pragma unroll
        for (int i = 0; i < 5; i++) {
            const float io = bjoc[i] + Obuf[sm * IST + ob + i];
            om[i] = aoc[i] * om[i] + (1.f - aoc[i]) * io;
        }
        float mx = om[0];
#pragma unroll
        for (int i = 1; i < 5; i++) mx = fmaxf(mx, om[i]);
        mx = fmaxf(mx, __shfl_xor(mx, 1));
        mx = fmaxf(mx, __shfl_xor(mx, 2));
        float se = 0.f;
#pragma unroll
        for (int i = 0; i < 5; i++) { e[i] = __expf(om[i] - mx); se += e[i]; }
        se += __shfl_xor(se, 1);
        se += __shfl_xor(se, 2);
#pragma unroll
        for (int i = 0; i < 5; i++) out[(r0 + sm) * ON + ob + i] = accs[i] + e[i] / se;
    }

    // spike-rate outputs
#pragma unroll
    for (int i = 0; i < 8; i++) {
        const float c1v = (float)((s1cp[i >> 1] >> (16 * (i & 1))) & 0xffffu);
        const float c2v = (float)((s2cp[i >> 1] >> (16 * (i & 1))) & 0xffffu);
        out[5120 + (r0 + um) * HN + hb + i] = c1v * (1.f / 250.f);
        out[5120 + 32768 + (r0 + um) * HN + hb + i] = c2v * (1.f / 250.f);
    }
}

// ---------------------------------------------------------------------------
extern "C" void kernel_launch(void* const* d_in, const int* in_sizes, int n_in,
                              void* d_out, int out_size, void* d_ws, size_t ws_size,
                              hipStream_t stream) {
    const float* x        = (const float*)d_in[0];
    const float* mask     = (const float*)d_in[1];
    const float* w_ih1    = (const float*)d_in[2];
    const float* b_ih1    = (const float*)d_in[3];
    const float* w_h1h1   = (const float*)d_in[4];
    const float* b_h1h1   = (const float*)d_in[5];
    const float* w_h1h2   = (const float*)d_in[6];
    const float* b_h1h2   = (const float*)d_in[7];
    const float* w_h2h2   = (const float*)d_in[8];
    const float* b_h2h2   = (const float*)d_in[9];
    const float* w_h2o    = (const float*)d_in[10];
    const float* b_h2o    = (const float*)d_in[11];
    const float* tau_adp1 = (const float*)d_in[12];
    const float* tau_adp2 = (const float*)d_in[13];
    const float* taum1    = (const float*)d_in[14];
    const float* taum2    = (const float*)d_in[15];
    const float* taumo    = (const float*)d_in[16];
    const float* h1m0     = (const float*)d_in[17];
    const float* h2m0     = (const float*)d_in[18];
    const float* om0      = (const float*)d_in[19];
    float* out = (float*)d_out;
    float* ws  = (float*)d_ws;

    float* xin = ws + XIN_OFF;

    gemm_in<<<1000, 256, 0, stream>>>(x, w_ih1, b_ih1, b_h1h1, xin);
    snn_scan<<<16, 256, 0, stream>>>(xin, mask, w_h1h1, w_h1h2, b_h1h2, w_h2h2,
                                     b_h2h2, w_h2o, b_h2o, tau_adp1, tau_adp2,
                                     taum1, taum2, taumo, h1m0, h2m0, om0, out);
}

// Round 4
// 655.819 us; speedup vs baseline: 2.4709x; 1.6110x over previous
//
#include <hip/hip_runtime.h>
#include <math.h>

#define TT 250
#define BT 256
#define HN 128
#define ON 20
#define KIN 700
#define NKT 22

// ws layout (float offsets): xin[250*256*128] | packed W hi | packed W lo
#define XIN_OFF 0
#define WPKH_OFF 8192000   // 45056 floats (90112 bf16)
#define WPKL_OFF 8237056   // 45056 floats

typedef __attribute__((ext_vector_type(8))) short bf16x8;
typedef __attribute__((ext_vector_type(4))) float f32x4;

__device__ __forceinline__ unsigned short bf16rne(float f) {
    unsigned u = __float_as_uint(f);
    unsigned r = u + 0x7fffu + ((u >> 16) & 1u);
    return (unsigned short)(r >> 16);
}
__device__ __forceinline__ void hilo(float v, short& h, short& l) {
    unsigned short hh = bf16rne(v);
    float vh = __uint_as_float((unsigned)hh << 16);
    h = (short)hh;
    l = (short)bf16rne(v - vh);
}

// ---------------------------------------------------------------------------
// pack w_ih1 (700x128, zero-pad K to 704) into MFMA B-frag order, hi/lo bf16.
// frag element (k,c): dst_frag = (kt*8+nt)*64 + qq*16+li, elem j
// ---------------------------------------------------------------------------
__global__ __launch_bounds__(256) void packw(const float* __restrict__ w,
                                             unsigned short* __restrict__ ph,
                                             unsigned short* __restrict__ pl) {
    int i = blockIdx.x * 256 + threadIdx.x;   // 352*256 = 90112 = 704*128
    int k = i >> 7, c = i & 127;
    float v = (k < KIN) ? w[k * HN + c] : 0.f;
    short h, l;
    hilo(v, h, l);
    int dst = (((k >> 5) * 8 + (c >> 4)) * 64 + (((k >> 3) & 3) * 16 + (c & 15))) * 8 + (k & 7);
    ph[dst] = (unsigned short)h;
    pl[dst] = (unsigned short)l;
}

// ---------------------------------------------------------------------------
// input projection via MFMA, no LDS / no barriers. Wave w of each block does
// rows m0+16w..+15 x all 128 cols, K=704 in 22 chunks. A loaded per-lane from
// x and split hi/lo in-register; B frags from the packed workspace (L2-hot).
// Biases b_ih1 + b_h1h1 folded into xin.
// ---------------------------------------------------------------------------
__global__ __launch_bounds__(256) void gemm_in(const float* __restrict__ x,
        const bf16x8* __restrict__ wph, const bf16x8* __restrict__ wpl,
        const float* __restrict__ bias1, const float* __restrict__ bias2,
        float* __restrict__ xin) {
    const int tid = threadIdx.x;
    const int w = tid >> 6, lane = tid & 63;
    const int q = lane >> 4, li = lane & 15;
    const long mrow = (long)blockIdx.x * 64 + w * 16 + li;
    const float* xr = x + mrow * KIN + q * 8;

    float b12[8];
#pragma unroll
    for (int nt = 0; nt < 8; nt++) {
        int col = nt * 16 + li;
        b12[nt] = bias1[col] + bias2[col];
    }

    f32x4 acc[8];
#pragma unroll
    for (int nt = 0; nt < 8; nt++) acc[nt] = (f32x4){0.f, 0.f, 0.f, 0.f};

    for (int kt = 0; kt < NKT; kt++) {
        float av[8];
        const float* p = xr + kt * 32;
        *(float4*)&av[0] = *(const float4*)p;
        if (kt == NKT - 1 && q == 3) {           // k 700..703 pad
            av[4] = 0.f; av[5] = 0.f; av[6] = 0.f; av[7] = 0.f;
        } else {
            *(float4*)&av[4] = *(const float4*)(p + 4);
        }
        bf16x8 ah, al;
#pragma unroll
        for (int j = 0; j < 8; j++) {
            short h, l;
            hilo(av[j], h, l);
            ah[j] = h; al[j] = l;
        }
#pragma unroll
        for (int nt = 0; nt < 8; nt++) {
            bf16x8 bh = wph[(kt * 8 + nt) * 64 + lane];
            bf16x8 bl = wpl[(kt * 8 + nt) * 64 + lane];
            acc[nt] = __builtin_amdgcn_mfma_f32_16x16x32_bf16(ah, bh, acc[nt], 0, 0, 0);
            acc[nt] = __builtin_amdgcn_mfma_f32_16x16x32_bf16(al, bh, acc[nt], 0, 0, 0);
            acc[nt] = __builtin_amdgcn_mfma_f32_16x16x32_bf16(ah, bl, acc[nt], 0, 0, 0);
        }
    }

#pragma unroll
    for (int r = 0; r < 4; r++) {
        int m = blockIdx.x * 64 + w * 16 + q * 4 + r;
        int bq = (int)(((unsigned long long)m * 67109ull) >> 24);  // m/250, exact for m<3.2M
        int tt = m - bq * 250;
        float* dst = xin + ((size_t)tt * BT + bq) * HN;
#pragma unroll
        for (int nt = 0; nt < 8; nt++) dst[nt * 16 + li] = acc[nt][r] + b12[nt];
    }
}

// ---------------------------------------------------------------------------
// scan v5: 16 blocks x 512 thr (8 waves, 2/SIMD). Wave w owns cols w*16..+15.
// Per step: phase1 = {W11,W22,(WHO on w6/w7)} MFMA + om update + layer-1 LIF
// update in C-layout + S1 frag write; B1; phase2 = W12 MFMA + (softmax on w7)
// + layer-2 LIF + S2 frag write; B2. W22 result and om state stay in regs.
// Spikes exchanged as bf16 frags: sA1 double-buffered (read+write same phase).
// ---------------------------------------------------------------------------
__global__ __launch_bounds__(512, 2) void snn_scan(
    const float* __restrict__ xin, const float* __restrict__ mask,
    const float* __restrict__ w_h1h1, const float* __restrict__ w_h1h2,
    const float* __restrict__ b_h1h2, const float* __restrict__ w_h2h2,
    const float* __restrict__ b_h2h2, const float* __restrict__ w_h2o,
    const float* __restrict__ b_h2o, const float* __restrict__ tau_adp1,
    const float* __restrict__ tau_adp2, const float* __restrict__ taum1,
    const float* __restrict__ taum2, const float* __restrict__ taumo,
    const float* __restrict__ h1m0, const float* __restrict__ h2m0,
    const float* __restrict__ om0, float* __restrict__ out) {

    __shared__ __align__(16) unsigned short sA1[2 * 2048];  // S1 frags, dbuf
    __shared__ __align__(16) unsigned short sA2[2048];      // S2 frags
    __shared__ float omb[16 * ON];
    __shared__ float red[8];

    const int tid = threadIdx.x;
    const int w = tid >> 6, lane = tid & 63;
    const int q = lane >> 4, li = lane & 15;
    const int col = w * 16 + li;          // this lane's neuron column
    const int r0 = blockIdx.x * 16;       // batch-row base

    // ---- weight fragments (register-resident, hi/lo bf16) ----
    bf16x8 h11[4], l11[4], h22[4], l22[4], h12[4], l12[4], hO[4], lO[4];
    const int ocol = (w == 6) ? li : 16 + li;         // WHO col (w6: 0-15, w7: 16-19)
    const bool oval = (w >= 6) && (ocol < ON);
    float pn = 0.f;
#pragma unroll
    for (int kt = 0; kt < 4; kt++) {
#pragma unroll
        for (int j = 0; j < 8; j++) {
            const int k = kt * 32 + q * 8 + j;
            const int idx = k * HN + col;
            float v11 = w_h1h1[idx] * mask[idx];
            float v22 = w_h2h2[idx] * mask[HN * HN + idx];
            float v12 = w_h1h2[idx];
            pn += fabsf(v11) + fabsf(v22);
            short hh, ll;
            hilo(v11, hh, ll); h11[kt][j] = hh; l11[kt][j] = ll;
            hilo(v22, hh, ll); h22[kt][j] = hh; l22[kt][j] = ll;
            hilo(v12, hh, ll); h12[kt][j] = hh; l12[kt][j] = ll;
            float vO = oval ? w_h2o[k * ON + ocol] : 0.f;
            hilo(vO, hh, ll); hO[kt][j] = hh; lO[kt][j] = ll;
        }
    }

    // ---- per-lane constants & state (4 rows x 1 col each) ----
    const float a1 = expf(-1.f / taum1[col]);
    const float r1 = expf(-1.f / tau_adp1[col]);
    const float a2 = expf(-1.f / taum2[col]);
    const float r2 = expf(-1.f / tau_adp2[col]);
    const float cc2 = b_h1h2[col] + b_h2h2[col];
    float h1m[4], h2m[4], b1[4], b2[4], c1[4], c2n[4];
    unsigned s1bits = 0, s2bits = 0;
#pragma unroll
    for (int r = 0; r < 4; r++) {
        h1m[r] = h1m0[(r0 + q * 4 + r) * HN + col];
        h2m[r] = h2m0[(r0 + q * 4 + r) * HN + col];
        b1[r] = 0.01f; b2[r] = 0.01f; c1[r] = 0.f; c2n[r] = 0.f;
    }
    const float ao = oval ? expf(-1.f / taumo[ocol]) : 0.f;
    const float bo = oval ? b_h2o[ocol] : 0.f;
    float om[4];
#pragma unroll
    for (int r = 0; r < 4; r++)
        om[r] = oval ? om0[(r0 + q * 4 + r) * ON + ocol] : 0.f;
    const int sm = lane >> 2, ob = (lane & 3) * 5;    // w7 softmax roles
    float accs[5] = {0.f, 0.f, 0.f, 0.f, 0.f};

    // zero spike frags (buffer 0 of sA1, sA2)
    {
        unsigned* z1 = (unsigned*)sA1;
        unsigned* z2 = (unsigned*)sA2;
        z1[tid] = 0u; z1[tid + 512] = 0u;
        z2[tid] = 0u; z2[tid + 512] = 0u;
    }

    // A_norm: exact f32 sum of |masked| weights, each element once
#pragma unroll
    for (int off = 32; off > 0; off >>= 1) pn += __shfl_down(pn, off);
    if (lane == 0) red[w] = pn;
    __syncthreads();
    if (tid == 0 && blockIdx.x == 0) {
        float s = 0.f;
#pragma unroll
        for (int i = 0; i < 8; i++) s += red[i];
        out[70656] = s;
    }

    // spike frag write index (this lane's 4 elements: +r*8)
    const int wbase = (w >> 1) * 512 + (((2 * w + (li >> 3)) & 3) * 16 + q * 4) * 8 + (li & 7);

    const bf16x8* sa1v = (const bf16x8*)sA1;
    const bf16x8* sa2v = (const bf16x8*)sA2;
    const unsigned short ONE = 0x3F80u;

    for (int t = 0; t < TT; t++) {
        const int rb = (t & 1) * 256;          // sA1 read base (bf16x8 units)
        const int wb = ((t + 1) & 1) * 2048;   // sA1 write base (shorts)

        // xin loads for this step (consumed after ~640cyc of MFMA, no barrier between)
        float xt[4];
#pragma unroll
        for (int r = 0; r < 4; r++)
            xt[r] = xin[((size_t)t * BT + r0 + q * 4 + r) * HN + col];

        // ================= phase 1 =================
        bf16x8 f1[4], f2[4];
#pragma unroll
        for (int kt = 0; kt < 4; kt++) {
            f1[kt] = sa1v[rb + kt * 64 + lane];
            f2[kt] = sa2v[kt * 64 + lane];
        }
        f32x4 aI = {0.f, 0.f, 0.f, 0.f}, aG = {0.f, 0.f, 0.f, 0.f};
#pragma unroll
        for (int kt = 0; kt < 4; kt++) {
            aI = __builtin_amdgcn_mfma_f32_16x16x32_bf16(f1[kt], h11[kt], aI, 0, 0, 0);
            aI = __builtin_amdgcn_mfma_f32_16x16x32_bf16(f1[kt], l11[kt], aI, 0, 0, 0);
            aG = __builtin_amdgcn_mfma_f32_16x16x32_bf16(f2[kt], h22[kt], aG, 0, 0, 0);
            aG = __builtin_amdgcn_mfma_f32_16x16x32_bf16(f2[kt], l22[kt], aG, 0, 0, 0);
        }
        if (w >= 6) {
            f32x4 aO = {0.f, 0.f, 0.f, 0.f};
#pragma unroll
            for (int kt = 0; kt < 4; kt++) {
                aO = __builtin_amdgcn_mfma_f32_16x16x32_bf16(f2[kt], hO[kt], aO, 0, 0, 0);
                aO = __builtin_amdgcn_mfma_f32_16x16x32_bf16(f2[kt], lO[kt], aO, 0, 0, 0);
            }
            if (t >= 1) {   // om update for step t-1 (io = S2(t-1)@WHO)
#pragma unroll
                for (int r = 0; r < 4; r++) {
                    om[r] = ao * om[r] + (1.f - ao) * (bo + aO[r]);
                    if (oval) omb[(q * 4 + r) * ON + ocol] = om[r];
                }
            }
        }
        // layer-1 LIF update (in C-layout: rows q*4+r, col)
#pragma unroll
        for (int r = 0; r < 4; r++) {
            const float sv = (float)((s1bits >> r) & 1u);
            const float i1 = xt[r] + aI[r];       // biases folded into xin
            b1[r] = r1 * b1[r] + (1.f - r1) * sv;
            const float B = 0.01f + 1.8f * b1[r];
            h1m[r] = a1 * h1m[r] + (1.f - a1) * i1 - B * sv;
            const bool sp = (h1m[r] - B) > 0.f;
            s1bits = sp ? (s1bits | (1u << r)) : (s1bits & ~(1u << r));
            c1[r] += sp ? 1.f : 0.f;
            sA1[wb + wbase + r * 8] = sp ? ONE : (unsigned short)0;
        }
        __syncthreads();  // B1: S1 frags + omb ready

        // ================= phase 2 =================
        bf16x8 g1[4];
#pragma unroll
        for (int kt = 0; kt < 4; kt++) g1[kt] = sa1v[(wb >> 3) + kt * 64 + lane];
        f32x4 aJ = {0.f, 0.f, 0.f, 0.f};
#pragma unroll
        for (int kt = 0; kt < 4; kt++) {
            aJ = __builtin_amdgcn_mfma_f32_16x16x32_bf16(g1[kt], h12[kt], aJ, 0, 0, 0);
            aJ = __builtin_amdgcn_mfma_f32_16x16x32_bf16(g1[kt], l12[kt], aJ, 0, 0, 0);
        }
        if (w == 7 && t >= 12) {   // softmax accumulate for step t-1
            float v[5], e[5];
            float mx = -1e30f;
#pragma unroll
            for (int i = 0; i < 5; i++) { v[i] = omb[sm * ON + ob + i]; mx = fmaxf(mx, v[i]); }
            mx = fmaxf(mx, __shfl_xor(mx, 1));
            mx = fmaxf(mx, __shfl_xor(mx, 2));
            float se = 0.f;
#pragma unroll
            for (int i = 0; i < 5; i++) { e[i] = __expf(v[i] - mx); se += e[i]; }
            se += __shfl_xor(se, 1);
            se += __shfl_xor(se, 2);
            const float inv = 1.f / se;
#pragma unroll
            for (int i = 0; i < 5; i++) accs[i] += e[i] * inv;
        }
        // layer-2 LIF update
#pragma unroll
        for (int r = 0; r < 4; r++) {
            const float sv = (float)((s2bits >> r) & 1u);
            const float i2 = aJ[r] + aG[r] + cc2;
            b2[r] = r2 * b2[r] + (1.f - r2) * sv;
            const float B = 0.01f + 1.8f * b2[r];
            h2m[r] = a2 * h2m[r] + (1.f - a2) * i2 - B * sv;
            const bool sp = (h2m[r] - B) > 0.f;
            s2bits = sp ? (s2bits | (1u << r)) : (s2bits & ~(1u << r));
            c2n[r] += sp ? 1.f : 0.f;
            sA2[wbase + r * 8] = sp ? ONE : (unsigned short)0;
        }
        __syncthreads();  // B2: S2 frags ready
    }

    // ---- tail: om + softmax for step 249 ----
    if (w >= 6) {
        bf16x8 f2[4];
#pragma unroll
        for (int kt = 0; kt < 4; kt++) f2[kt] = sa2v[kt * 64 + lane];
        f32x4 aO = {0.f, 0.f, 0.f, 0.f};
#pragma unroll
        for (int kt = 0; kt < 4; kt++) {
            aO = __builtin_amdgcn_mfma_f32_16x16x32_bf16(f2[kt], hO[kt], aO, 0, 0, 0);
            aO = __builtin_amdgcn_mfma_f32_16x16x32_bf16(f2[kt], lO[kt], aO, 0, 0, 0);
        }
#pragma unroll
        for (int r = 0; r < 4; r++) {
            om[r] = ao * om[r] + (1.f - ao) * (bo + aO[r]);
            if (oval) omb[(q * 4 + r) * ON + ocol] = om[r];
        }
    }
    __syncthreads();
    if (w == 7) {
        float v[5], e[5];
        float mx = -1e30f;
#pragma unroll
        for (int i = 0; i < 5; i++) { v[i] = omb[sm * ON + ob + i]; mx = fmaxf(mx, v[i]); }
        mx = fmaxf(mx, __shfl_xor(mx, 1));
        mx = fmaxf(mx, __shfl_xor(mx, 2));
        float se = 0.f;
#pragma unroll
        for (int i = 0; i < 5; i++) { e[i] = __expf(v[i] - mx); se += e[i]; }
        se += __shfl_xor(se, 1);
        se += __shfl_xor(se, 2);
        const float inv = 1.f / se;
#pragma unroll
        for (int i = 0; i < 5; i++) out[(r0 + sm) * ON + ob + i] = accs[i] + e[i] * inv;
    }
    // spike rates
#pragma unroll
    for (int r = 0; r < 4; r++) {
        out[5120 + (r0 + q * 4 + r) * HN + col] = c1[r] * (1.f / 250.f);
        out[37888 + (r0 + q * 4 + r) * HN + col] = c2n[r] * (1.f / 250.f);
    }
}

// ---------------------------------------------------------------------------
extern "C" void kernel_launch(void* const* d_in, const int* in_sizes, int n_in,
                              void* d_out, int out_size, void* d_ws, size_t ws_size,
                              hipStream_t stream) {
    const float* x        = (const float*)d_in[0];
    const float* mask     = (const float*)d_in[1];
    const float* w_ih1    = (const float*)d_in[2];
    const float* b_ih1    = (const float*)d_in[3];
    const float* w_h1h1   = (const float*)d_in[4];
    const float* b_h1h1   = (const float*)d_in[5];
    const float* w_h1h2   = (const float*)d_in[6];
    const float* b_h1h2   = (const float*)d_in[7];
    const float* w_h2h2   = (const float*)d_in[8];
    const float* b_h2h2   = (const float*)d_in[9];
    const float* w_h2o    = (const float*)d_in[10];
    const float* b_h2o    = (const float*)d_in[11];
    const float* tau_adp1 = (const float*)d_in[12];
    const float* tau_adp2 = (const float*)d_in[13];
    const float* taum1    = (const float*)d_in[14];
    const float* taum2    = (const float*)d_in[15];
    const float* taumo    = (const float*)d_in[16];
    const float* h1m0     = (const float*)d_in[17];
    const float* h2m0     = (const float*)d_in[18];
    const float* om0      = (const float*)d_in[19];
    float* out = (float*)d_out;
    float* ws  = (float*)d_ws;

    float* xin = ws + XIN_OFF;
    unsigned short* wph = (unsigned short*)(ws + WPKH_OFF);
    unsigned short* wpl = (unsigned short*)(ws + WPKL_OFF);

    packw<<<352, 256, 0, stream>>>(w_ih1, wph, wpl);
    gemm_in<<<1000, 256, 0, stream>>>(x, (const bf16x8*)wph, (const bf16x8*)wpl,
                                      b_ih1, b_h1h1, xin);
    snn_scan<<<16, 512, 0, stream>>>(xin, mask, w_h1h1, w_h1h2, b_h1h2, w_h2h2,
                                     b_h2h2, w_h2o, b_h2o, tau_adp1, tau_adp2,
                                     taum1, taum2, taumo, h1m0, h2m0, om0, out);
}